// Round 11
// baseline (177.826 us; speedup 1.0000x reference)
//
#include <hip/hip_runtime.h>

typedef float  f32x4  __attribute__((ext_vector_type(4)));
typedef __bf16 bf16x8 __attribute__((ext_vector_type(8)));
typedef unsigned short u16;
typedef u16 u16x8 __attribute__((ext_vector_type(8)));
typedef u16 u16x4 __attribute__((ext_vector_type(4)));
typedef unsigned u32x4 __attribute__((ext_vector_type(4)));

#define HEADS 16
#define DIM   128
#define QT    64    // q-rows per block (4 waves x 16 rows)
#define KTILE 64
#define PSTR  72    // fallback P staging row stride (u16)
// fallback kernel strides
#define KSTR  136
#define VSTR  68

__device__ __forceinline__ u16 f2bf(float f) {
    unsigned u = __builtin_bit_cast(unsigned, f);
    u += 0x7FFFu + ((u >> 16) & 1u);   // RNE
    return (u16)(u >> 16);
}

// async 16B global->LDS DMA (zero VGPR cost); lane i lands at ldsbase + i*16
__device__ __forceinline__ void dma16(const void* g, void* l) {
    auto* gp = (const __attribute__((address_space(1))) unsigned*)(uintptr_t)g;
    auto* lp = (__attribute__((address_space(3))) unsigned*)(uintptr_t)l;
    __builtin_amdgcn_global_load_lds(gp, lp, 16, 0, 0);
}

// pinned 16B global load: asm volatile so the compiler can neither sink the
// issue point nor forget the VGPRs (R5 lesson: plain loads got rescheduled).
// NOTE: result is NOT vmcnt-tracked by the compiler -> consumer must be
// preceded by an explicit s_waitcnt vmcnt(N).
__device__ __forceinline__ u32x4 gload16(const void* p) {
    u32x4 d;
    asm volatile("global_load_dwordx4 %0, %1, off" : "=v"(d) : "v"(p) : "memory");
    return d;
}

// pack two f32 -> one u32 of 2 bf16 (RNE), in-register
__device__ __forceinline__ unsigned cvtpk(float lo, float hi) {
    unsigned r;
    asm("v_cvt_pk_bf16_f32 %0, %1, %2" : "=v"(r) : "v"(lo), "v"(hi));
    return r;
}

// ---------------- fused prep kernel: fp32 -> bf16, tiled + XOR-swizzled -----
// One block per (h, tile). Produces BOTH the K image and the V^T image.
// K tile image (16KB): row r(key 0..63) * 256B; 16B-group g(d/8) at (g ^ (r&7))
// V tile image (16KB), TRANSPOSED via LDS: row d(0..127)*128B; group g2(k/8) at (g2 ^ (d&7))
__global__ __launch_bounds__(256) void prep_kv(
    const float* __restrict__ K, const float* __restrict__ V,
    u16* __restrict__ KB, u16* __restrict__ VB, int S)
{
    __shared__ __align__(16) u16 T[128 * 72];     // [d][k], stride 72 (pad)
    int nt = S >> 6;
    int tile = blockIdx.x % nt, h = blockIdx.x / nt;
    int t = threadIdx.x;
    long tb = (long)(h * nt + tile) * 8192;       // u16 per tile

    // ---- K part: straight global->global swizzled copy+convert
    const float* ksrc = K + ((long)(h * S + tile * 64)) * DIM;
#pragma unroll
    for (int it = 0; it < 4; ++it) {
        int idx = t + it * 256;                   // 16B output group id 0..1023
        int g = idx & 15, r = idx >> 4;
        const float* src = ksrc + (long)r * DIM + g * 8;
        f32x4 a = *(const f32x4*)src;
        f32x4 b = *(const f32x4*)(src + 4);
        u16x8 o;
        o[0]=f2bf(a[0]); o[1]=f2bf(a[1]); o[2]=f2bf(a[2]); o[3]=f2bf(a[3]);
        o[4]=f2bf(b[0]); o[5]=f2bf(b[1]); o[6]=f2bf(b[2]); o[7]=f2bf(b[3]);
        *(u16x8*)&KB[tb + r * 128 + ((g ^ (r & 7)) << 3)] = o;
    }

    // ---- V part: coalesced reads, LDS transpose, coalesced writes
    int col4 = (t & 31) * 4;                      // d base
    int row  = t >> 5;                            // k base 0..7
    const float* vsrc = V + ((long)(h * S + tile * 64)) * DIM;
#pragma unroll
    for (int it = 0; it < 8; ++it) {
        int k = row + it * 8;
        f32x4 x = *(const f32x4*)(vsrc + (long)k * DIM + col4);
        T[(col4 + 0) * 72 + k] = f2bf(x[0]);
        T[(col4 + 1) * 72 + k] = f2bf(x[1]);
        T[(col4 + 2) * 72 + k] = f2bf(x[2]);
        T[(col4 + 3) * 72 + k] = f2bf(x[3]);
    }
    __syncthreads();
#pragma unroll
    for (int it = 0; it < 4; ++it) {
        int idx = t + it * 256;                   // 16B chunk id 0..1023
        int d = idx >> 3, g2 = idx & 7;
        u16x8 o = *(const u16x8*)&T[d * 72 + g2 * 8];
        *(u16x8*)&VB[tb + d * 64 + ((g2 ^ (d & 7)) << 3)] = o;
    }
}

// ------- main flash kernel: 3 blocks/CU; K dbuf DMA + V pinned reg-staging --
__global__ __launch_bounds__(256, 3) void fa_main(
    const float* __restrict__ Q, const u16* __restrict__ KB,
    const u16* __restrict__ VB, const void* __restrict__ cu_raw,
    int n_cu, float* __restrict__ O, int S, int n_qb)
{
    __shared__ __align__(16) u16 Kb[2][64 * 128];     // 2x16KB swizzled K tiles
    __shared__ __align__(16) u16 Vt[128 * 64];        // 1x16KB V^T tile
    __shared__ int cu_s[32];

    const int tid  = threadIdx.x;
    const int wave = tid >> 6, lane = tid & 63;
    const int quad = lane >> 4, l16 = lane & 15;
    const int h  = blockIdx.x & (HEADS - 1);          // heads vary fastest:
    const int qb = (n_qb - 1) - (blockIdx.x >> 4);    // all long blocks first
    const int q0 = qb * QT;

    {   // cu_seqlens int64/int32 sniff
        const int* cu32 = (const int*)cu_raw;
        bool is64 = (cu32[1] == 0);
        for (int t = tid; t < n_cu; t += blockDim.x)
            cu_s[t] = is64 ? (int)((const long long*)cu_raw)[t] : cu32[t];
    }
    __syncthreads();

    const float sc2 = 0.08838834764831845f * 1.4426950408889634f; // scale*log2e
    const long hb = (long)h * S * DIM;
    const long hk = (long)h * (S >> 6) * 8192;        // u16 per head in KB/VB
    const int qend = q0 + QT;

    // swapped QK^T: this lane's q-row is l16-based (one per lane)
    const int qi_l = q0 + wave * 16 + l16;
    int qs = 0;
    for (int j = 0; j < n_cu; ++j) if (cu_s[j] <= qi_l) qs = cu_s[j];
    int q0s = 0;
    for (int j = 0; j < n_cu; ++j) if (cu_s[j] <= q0) q0s = cu_s[j];
    const int drange = qi_l - qs;                     // mask range (>= 0)

    // wave-uniform skip bounds: qs monotone in qi -> lane 0 holds the min
    const int wqmin = __builtin_amdgcn_readfirstlane(qs);
    const int wqmax = q0 + wave * 16 + 15;

    // Q fragments, fp32 -> bf16 once (B operand of swapped QK^T)
    bf16x8 qfrag[4];
    {
        const float* qp = Q + hb + (long)qi_l * DIM + quad * 8;
#pragma unroll
        for (int kk = 0; kk < 4; ++kk) {
            f32x4 x = *(const f32x4*)(qp + kk * 32);
            f32x4 y = *(const f32x4*)(qp + kk * 32 + 4);
            u16x8 u;
            u[0]=f2bf(x[0]); u[1]=f2bf(x[1]); u[2]=f2bf(x[2]); u[3]=f2bf(x[3]);
            u[4]=f2bf(y[0]); u[5]=f2bf(y[1]); u[6]=f2bf(y[2]); u[7]=f2bf(y[3]);
            qfrag[kk] = __builtin_bit_cast(bf16x8, u);
        }
    }

    f32x4 acc[8];
#pragma unroll
    for (int dt = 0; dt < 8; ++dt) acc[dt] = (f32x4){0.f, 0.f, 0.f, 0.f};
    float lsum = 0.f;                                 // row-sum (VALU, not MFMA)

    const int t0 = (q0s & ~(KTILE - 1)) >> 6;
    const int ntile = (qend >> 6) - t0;               // >= 1 always
    const u16* ksrc = KB + hk;
    const u16* vsrc = VB + hk;

    // prologue: stage tile t0 (4 K-chunks + 4 V-chunks per wave, via DMA)
    {
        long off = (long)t0 * 8192;
#pragma unroll
        for (int c = 0; c < 4; ++c) {
            int ch = wave * 4 + c;                    // 0..15
            dma16(ksrc + off + ch * 512 + lane * 8, &Kb[0][ch * 512]);
            dma16(vsrc + off + ch * 512 + lane * 8, &Vt[ch * 512]);
        }
    }

    for (int i = 0; i < ntile; ++i) {
        const int cur = i & 1;
        // Prefetch tile i+1, issued a FULL tile ahead:
        //   V[i+1] -> 16 VGPRs via PINNED asm loads (image pre-swizzled, so a
        //             linear copy); ds_write'd to Vt after the post-PV barrier.
        //   K[i+1] -> Kb[cur^1] via global_load_lds DMA.
        // vmcnt(8) leaves the 8 newest (V[i+1]+K[i+1]) in flight and drains
        // tile-i staging (prologue or previous iteration).
        u32x4 vreg[4];
        if (i + 1 < ntile) {
            long off = (long)(t0 + i + 1) * 8192;
            const u16* vsp = vsrc + off + tid * 8;    // chunk c: contiguous 4KB
#pragma unroll
            for (int c = 0; c < 4; ++c)
                vreg[c] = gload16(vsp + c * 2048);
#pragma unroll
            for (int c = 0; c < 4; ++c) {
                int ch = wave * 4 + c;
                dma16(ksrc + off + ch * 512 + lane * 8, &Kb[cur ^ 1][ch * 512]);
            }
            asm volatile("s_waitcnt vmcnt(8)" ::: "memory");
        } else {
            asm volatile("s_waitcnt vmcnt(0)" ::: "memory");
        }
        // drain our V[i] ds_writes (prev iter), then publish via barrier
        asm volatile("s_waitcnt lgkmcnt(0)" ::: "memory");
        __builtin_amdgcn_s_barrier();                 // K[i] and V[i] visible

        const int kt = (t0 + i) << 6;
        // wave-level skip: tile fully above this wave's diagonal or fully
        // before every row's document -> all-zero P, skip compute entirely.
        if (kt <= wqmax && kt + KTILE > wqmin) {
            const u16* kb = &Kb[cur][0];

            // ---- S^T = K Q^T (swapped): lane l16 = q-row, quad*4+r = k.
            // exp2/mask/cvtpk for sub-tile nt-1 interleaved after QK(nt).
            f32x4 sc[4];
            unsigned Ra[4], Rb[4];
            const int base0 = (kt - qs) + quad * 4;   // per-lane mask base
#pragma unroll
            for (int nt = 0; nt < 4; ++nt) sc[nt] = (f32x4){0.f, 0.f, 0.f, 0.f};

#define EXP2N(n)                                                              \
            {                                                                 \
                int b_ = base0 + (n) * 16;                                    \
                float p0 = ((unsigned)(b_ + 0) <= (unsigned)drange)           \
                               ? __builtin_amdgcn_exp2f(sc[n][0] * sc2) : 0.f;\
                float p1 = ((unsigned)(b_ + 1) <= (unsigned)drange)           \
                               ? __builtin_amdgcn_exp2f(sc[n][1] * sc2) : 0.f;\
                float p2 = ((unsigned)(b_ + 2) <= (unsigned)drange)           \
                               ? __builtin_amdgcn_exp2f(sc[n][2] * sc2) : 0.f;\
                float p3 = ((unsigned)(b_ + 3) <= (unsigned)drange)           \
                               ? __builtin_amdgcn_exp2f(sc[n][3] * sc2) : 0.f;\
                lsum += (p0 + p1) + (p2 + p3);                                \
                Ra[n] = cvtpk(p0, p1);                                        \
                Rb[n] = cvtpk(p2, p3);                                        \
            }

            __builtin_amdgcn_s_setprio(1);
#pragma unroll
            for (int nt = 0; nt < 4; ++nt) {
                // diagonal nt-skip: sub-tile fully above the wave's max row
                // has all-masked P -> its QK MFMAs are dead work.
                if (kt + nt * 16 <= wqmax) {
#pragma unroll
                    for (int kk = 0; kk < 4; ++kk) {
                        int row = nt * 16 + l16;
                        int g = kk * 4 + quad;
                        u16x8 bu = *(const u16x8*)&kb[row * 128 + ((g ^ (row & 7)) << 3)];
                        sc[nt] = __builtin_amdgcn_mfma_f32_16x16x32_bf16(
                            __builtin_bit_cast(bf16x8, bu), qfrag[kk], sc[nt], 0, 0, 0);
                    }
                }
                if (nt >= 1) EXP2N(nt - 1);
            }
            EXP2N(3);
#undef EXP2N

            // ---- O += P V
#pragma unroll
            for (int kk2 = 0; kk2 < 2; ++kk2) {
                unsigned a0 = Ra[2*kk2], a1 = Ra[2*kk2 + 1];
                unsigned b0 = Rb[2*kk2], b1 = Rb[2*kk2 + 1];
                asm("v_permlane32_swap_b32 %0, %1" : "+v"(a0), "+v"(a1));
                asm("v_permlane16_swap_b32 %0, %1" : "+v"(a0), "+v"(a1));
                asm("v_permlane32_swap_b32 %0, %1" : "+v"(b0), "+v"(b1));
                asm("v_permlane16_swap_b32 %0, %1" : "+v"(b0), "+v"(b1));
                u32x4 wv; wv[0] = a0; wv[1] = b0; wv[2] = a1; wv[3] = b1;
                bf16x8 ap = __builtin_bit_cast(bf16x8, wv);

                int g2 = kk2 * 4 + quad;
#pragma unroll
                for (int dt = 0; dt < 8; ++dt) {
                    int d = dt * 16 + l16;
                    u16x8 bu = *(const u16x8*)&Vt[(d << 6) + ((g2 ^ (d & 7)) << 3)];
                    acc[dt] = __builtin_amdgcn_mfma_f32_16x16x32_bf16(
                        ap, __builtin_bit_cast(bf16x8, bu), acc[dt], 0, 0, 0);
                }
            }
            __builtin_amdgcn_s_setprio(0);
        }

        __builtin_amdgcn_s_barrier();                 // all PV reads of Vt done
        if (i + 1 < ntile) {
            // V[i+1] regs -> Vt (linear, conflict-free). The asm loads are NOT
            // in the compiler's vmcnt model -> explicit wait. vmcnt(4) drains
            // the 4 V loads (oldest) and keeps K[i+1]'s 4 DMAs in flight.
            asm volatile("s_waitcnt vmcnt(4)" ::: "memory");
#pragma unroll
            for (int c = 0; c < 4; ++c)
                *(u32x4*)&Vt[tid * 8 + c * 2048] = vreg[c];
        }
    }

    // ---- epilogue: row-sum lives per-lane; reduce across the 4 quad copies
    float lred = lsum;
    lred += __shfl_xor(lred, 16, 64);
    lred += __shfl_xor(lred, 32, 64);                 // all lanes: rowsum(l16)
#pragma unroll
    for (int r = 0; r < 4; ++r) {
        float l = __shfl(lred, quad * 4 + r, 64);     // rowsum of row quad*4+r
        int qi = q0 + wave * 16 + quad * 4 + r;
        float inv = 1.f / l;
        float* op = O + hb + (long)qi * DIM + l16;
#pragma unroll
        for (int dt = 0; dt < 8; ++dt)
            op[dt * 16] = acc[dt][r] * inv;
    }
}

// ---------------- fallback (round-1 kernel, used only if ws too small) ------
__global__ __launch_bounds__(256, 2) void fa_fallback(
    const float* __restrict__ Q, const float* __restrict__ K,
    const float* __restrict__ V, const void* __restrict__ cu_raw,
    int n_cu, float* __restrict__ O, int S)
{
    __shared__ __align__(16) u16 Kb[KTILE * KSTR];
    __shared__ __align__(16) u16 Vt[DIM * VSTR];
    __shared__ __align__(16) u16 Pw[4][16 * PSTR];
    __shared__ int cu_s[32];

    const int tid  = threadIdx.x;
    const int wave = tid >> 6, lane = tid & 63;
    const int quad = lane >> 4, l16 = lane & 15;
    const int q0   = blockIdx.x * QT;
    const int h    = blockIdx.y;
    const int cg = tid & 31, rr = tid >> 5;
    const int dv = tid & 127, hiv = tid >> 7;

    {
        const int* cu32 = (const int*)cu_raw;
        bool is64 = (cu32[1] == 0);
        for (int t = tid; t < n_cu; t += blockDim.x)
            cu_s[t] = is64 ? (int)((const long long*)cu_raw)[t] : cu32[t];
    }
    __syncthreads();

    const long hb = (long)h * S * DIM;
    const float NEG_INF = -__builtin_inff();
    const float scale = 0.08838834764831845f;

    int qstart[4];
#pragma unroll
    for (int r = 0; r < 4; ++r) {
        int qi = q0 + wave * 16 + quad * 4 + r;
        int st = 0;
        for (int j = 0; j < n_cu; ++j) if (cu_s[j] <= qi) st = cu_s[j];
        qstart[r] = st;
    }
    int q0s = 0;
    for (int j = 0; j < n_cu; ++j) if (cu_s[j] <= q0) q0s = cu_s[j];

    bf16x8 qfrag[4];
    {
        const float* qp = Q + hb + (long)(q0 + wave * 16 + l16) * DIM + quad * 8;
#pragma unroll
        for (int kk = 0; kk < 4; ++kk) {
            f32x4 x = *(const f32x4*)(qp + kk * 32);
            f32x4 y = *(const f32x4*)(qp + kk * 32 + 4);
            u16x8 u;
            u[0]=f2bf(x[0]); u[1]=f2bf(x[1]); u[2]=f2bf(x[2]); u[3]=f2bf(x[3]);
            u[4]=f2bf(y[0]); u[5]=f2bf(y[1]); u[6]=f2bf(y[2]); u[7]=f2bf(y[3]);
            qfrag[kk] = __builtin_bit_cast(bf16x8, u);
        }
    }

    f32x4 acc[8];
#pragma unroll
    for (int dt = 0; dt < 8; ++dt) acc[dt] = (f32x4){0.f, 0.f, 0.f, 0.f};
    float m_r[4], l_r[4];
#pragma unroll
    for (int r = 0; r < 4; ++r) { m_r[r] = NEG_INF; l_r[r] = 0.f; }

    for (int kt = q0s & ~(KTILE - 1); kt < q0 + QT; kt += KTILE) {
        __syncthreads();
        {
#pragma unroll
            for (int it = 0; it < 8; ++it) {
                f32x4 kx = *(const f32x4*)(K + hb + (long)(kt + rr + it*8) * DIM + cg*4);
                u16x4 kb4;
                kb4[0]=f2bf(kx[0]); kb4[1]=f2bf(kx[1]);
                kb4[2]=f2bf(kx[2]); kb4[3]=f2bf(kx[3]);
                *(u16x4*)&Kb[(rr + it*8) * KSTR + cg*4] = kb4;
            }
#pragma unroll
            for (int p = 0; p < 8; ++p) {
                int kq = 2*p + hiv;
                const float* vp = V + hb + (long)(kt + kq*4) * DIM + dv;
                u16x4 w;
                w[0]=f2bf(vp[0]); w[1]=f2bf(vp[(long)DIM]);
                w[2]=f2bf(vp[(long)2*DIM]); w[3]=f2bf(vp[(long)3*DIM]);
                *(u16x4*)&Vt[dv * VSTR + kq*4] = w;
            }
        }
        __syncthreads();

        f32x4 sc[4];
#pragma unroll
        for (int nt = 0; nt < 4; ++nt) sc[nt] = (f32x4){0.f, 0.f, 0.f, 0.f};
#pragma unroll
        for (int kk = 0; kk < 4; ++kk)
#pragma unroll
            for (int nt = 0; nt < 4; ++nt) {
                u16x8 bu = *(const u16x8*)&Kb[(nt*16 + l16) * KSTR + kk*32 + quad*8];
                sc[nt] = __builtin_amdgcn_mfma_f32_16x16x32_bf16(
                    qfrag[kk], __builtin_bit_cast(bf16x8, bu), sc[nt], 0, 0, 0);
            }
#pragma unroll
        for (int nt = 0; nt < 4; ++nt) {
            int kj = kt + nt * 16 + l16;
#pragma unroll
            for (int r = 0; r < 4; ++r) {
                int qi = q0 + wave * 16 + quad * 4 + r;
                bool ok = (kj >= qstart[r]) && (kj <= qi);
                sc[nt][r] = ok ? sc[nt][r] * scale : NEG_INF;
            }
        }
        float mnew[4], alpha[4], rsum[4];
#pragma unroll
        for (int r = 0; r < 4; ++r) {
            float tm = fmaxf(fmaxf(sc[0][r], sc[1][r]), fmaxf(sc[2][r], sc[3][r]));
#pragma unroll
            for (int off = 1; off < 16; off <<= 1)
                tm = fmaxf(tm, __shfl_xor(tm, off, 64));
            float mn = fmaxf(m_r[r], tm);
            mnew[r]  = mn;
            alpha[r] = (mn == NEG_INF) ? 1.f : __expf(m_r[r] - mn);
            rsum[r]  = 0.f;
        }
#pragma unroll
        for (int nt = 0; nt < 4; ++nt)
#pragma unroll
            for (int r = 0; r < 4; ++r) {
                float pv = (sc[nt][r] == NEG_INF) ? 0.f : __expf(sc[nt][r] - mnew[r]);
                sc[nt][r] = pv;
                rsum[r] += pv;
            }
#pragma unroll
        for (int r = 0; r < 4; ++r) {
            float s = rsum[r];
#pragma unroll
            for (int off = 1; off < 16; off <<= 1) s += __shfl_xor(s, off, 64);
            l_r[r] = l_r[r] * alpha[r] + s;
            m_r[r] = mnew[r];
        }
#pragma unroll
        for (int dt = 0; dt < 8; ++dt)
#pragma unroll
            for (int r = 0; r < 4; ++r) acc[dt][r] *= alpha[r];

#pragma unroll
        for (int nt = 0; nt < 4; ++nt)
#pragma unroll
            for (int r = 0; r < 4; ++r)
                Pw[wave][(quad*4 + r) * PSTR + ((nt ^ quad) * 16 + l16)] = f2bf(sc[nt][r]);

#pragma unroll
        for (int kk2 = 0; kk2 < 2; ++kk2) {
            int colx = (kk2*32 + quad*8) ^ ((l16 >> 2) << 4);
            u16x8 au = *(const u16x8*)&Pw[wave][l16 * PSTR + colx];
            bf16x8 ap = __builtin_bit_cast(bf16x8, au);
#pragma unroll
            for (int dt = 0; dt < 8; ++dt) {
                int base = (dt*16 + l16) * VSTR + kk2*32 + quad*8;
                u16x4 lo = *(const u16x4*)&Vt[base];
                u16x4 hi = *(const u16x4*)&Vt[base + 4];
                u16x8 bu;
                bu[0]=lo[0]; bu[1]=lo[1]; bu[2]=lo[2]; bu[3]=lo[3];
                bu[4]=hi[0]; bu[5]=hi[1]; bu[6]=hi[2]; bu[7]=hi[3];
                acc[dt] = __builtin_amdgcn_mfma_f32_16x16x32_bf16(
                    ap, __builtin_bit_cast(bf16x8, bu), acc[dt], 0, 0, 0);
            }
        }
    }

#pragma unroll
    for (int r = 0; r < 4; ++r) {
        int qi = q0 + wave * 16 + quad * 4 + r;
        float inv = 1.f / l_r[r];
        float* op = O + hb + (long)qi * DIM + l16;
#pragma unroll
        for (int dt = 0; dt < 8; ++dt)
            op[dt * 16] = acc[dt][r] * inv;
    }
}

extern "C" void kernel_launch(void* const* d_in, const int* in_sizes, int n_in,
                              void* d_out, int out_size, void* d_ws, size_t ws_size,
                              hipStream_t stream) {
    const float* q = (const float*)d_in[0];
    const float* k = (const float*)d_in[1];
    const float* v = (const float*)d_in[2];
    const void* cu = d_in[3];
    int n_cu = in_sizes[3];
    int S = in_sizes[0] / (HEADS * DIM);
    size_t perMat = (size_t)HEADS * S * 256;      // bytes of bf16 tiles per matrix
    if (ws_size >= 2 * perMat) {
        u16* KB = (u16*)d_ws;
        u16* VB = (u16*)((char*)d_ws + perMat);
        prep_kv<<<dim3(HEADS * (S >> 6)), 256, 0, stream>>>(k, v, KB, VB, S);
        int n_qb = S / QT;
        fa_main<<<dim3(n_qb * HEADS), 256, 0, stream>>>(
            q, KB, VB, cu, n_cu, (float*)d_out, S, n_qb);
    } else {
        fa_fallback<<<dim3(S / QT, HEADS), 256, 0, stream>>>(
            q, k, v, cu, n_cu, (float*)d_out, S);
    }
}

// Round 13
// 176.540 us; speedup vs baseline: 1.0073x; 1.0073x over previous
//
#include <hip/hip_runtime.h>

typedef float  f32x4  __attribute__((ext_vector_type(4)));
typedef __bf16 bf16x8 __attribute__((ext_vector_type(8)));
typedef unsigned short u16;
typedef u16 u16x8 __attribute__((ext_vector_type(8)));
typedef u16 u16x4 __attribute__((ext_vector_type(4)));
typedef unsigned u32x4 __attribute__((ext_vector_type(4)));

#define HEADS 16
#define DIM   128
#define QT    64    // q-rows per block (4 waves x 16 rows)
#define KTILE 64
#define PSTR  72    // fallback P staging row stride (u16)
// fallback kernel strides
#define KSTR  136
#define VSTR  68

__device__ __forceinline__ u16 f2bf(float f) {
    unsigned u = __builtin_bit_cast(unsigned, f);
    u += 0x7FFFu + ((u >> 16) & 1u);   // RNE
    return (u16)(u >> 16);
}

// async 16B global->LDS DMA (zero VGPR cost); lane i lands at ldsbase + i*16
__device__ __forceinline__ void dma16(const void* g, void* l) {
    auto* gp = (const __attribute__((address_space(1))) unsigned*)(uintptr_t)g;
    auto* lp = (__attribute__((address_space(3))) unsigned*)(uintptr_t)l;
    __builtin_amdgcn_global_load_lds(gp, lp, 16, 0, 0);
}

// pack two f32 -> one u32 of 2 bf16 (RNE), in-register
__device__ __forceinline__ unsigned cvtpk(float lo, float hi) {
    unsigned r;
    asm("v_cvt_pk_bf16_f32 %0, %1, %2" : "=v"(r) : "v"(lo), "v"(hi));
    return r;
}

// ---------------- fused prep kernel: fp32 -> bf16, tiled + XOR-swizzled -----
// One block per (h, tile). Produces BOTH the K image and the V^T image.
// K tile image (16KB): row r(key 0..63) * 256B; 16B-group g(d/8) at (g ^ (r&7))
// V tile image (16KB), TRANSPOSED via LDS: row d(0..127)*128B; group g2(k/8) at (g2 ^ (d&7))
__global__ __launch_bounds__(256) void prep_kv(
    const float* __restrict__ K, const float* __restrict__ V,
    u16* __restrict__ KB, u16* __restrict__ VB, int S)
{
    __shared__ __align__(16) u16 T[128 * 72];     // [d][k], stride 72 (pad)
    int nt = S >> 6;
    int tile = blockIdx.x % nt, h = blockIdx.x / nt;
    int t = threadIdx.x;
    long tb = (long)(h * nt + tile) * 8192;       // u16 per tile

    // ---- K part: straight global->global swizzled copy+convert
    const float* ksrc = K + ((long)(h * S + tile * 64)) * DIM;
#pragma unroll
    for (int it = 0; it < 4; ++it) {
        int idx = t + it * 256;                   // 16B output group id 0..1023
        int g = idx & 15, r = idx >> 4;
        const float* src = ksrc + (long)r * DIM + g * 8;
        f32x4 a = *(const f32x4*)src;
        f32x4 b = *(const f32x4*)(src + 4);
        u16x8 o;
        o[0]=f2bf(a[0]); o[1]=f2bf(a[1]); o[2]=f2bf(a[2]); o[3]=f2bf(a[3]);
        o[4]=f2bf(b[0]); o[5]=f2bf(b[1]); o[6]=f2bf(b[2]); o[7]=f2bf(b[3]);
        *(u16x8*)&KB[tb + r * 128 + ((g ^ (r & 7)) << 3)] = o;
    }

    // ---- V part: coalesced reads, LDS transpose, coalesced writes
    int col4 = (t & 31) * 4;                      // d base
    int row  = t >> 5;                            // k base 0..7
    const float* vsrc = V + ((long)(h * S + tile * 64)) * DIM;
#pragma unroll
    for (int it = 0; it < 8; ++it) {
        int k = row + it * 8;
        f32x4 x = *(const f32x4*)(vsrc + (long)k * DIM + col4);
        T[(col4 + 0) * 72 + k] = f2bf(x[0]);
        T[(col4 + 1) * 72 + k] = f2bf(x[1]);
        T[(col4 + 2) * 72 + k] = f2bf(x[2]);
        T[(col4 + 3) * 72 + k] = f2bf(x[3]);
    }
    __syncthreads();
#pragma unroll
    for (int it = 0; it < 4; ++it) {
        int idx = t + it * 256;                   // 16B chunk id 0..1023
        int d = idx >> 3, g2 = idx & 7;
        u16x8 o = *(const u16x8*)&T[d * 72 + g2 * 8];
        *(u16x8*)&VB[tb + d * 64 + ((g2 ^ (d & 7)) << 3)] = o;
    }
}

// --- main flash kernel: single-buffered K&V (32KB), deep block-TLP/CU -------
// LDS = exactly 32KB/block -> up to 5 blocks/CU by LDS; launch_bounds(256,4)
// keeps VGPR <= 128 (spill-free); HW co-schedules 5 if VGPR allows.
// vmcnt(0) drain per tile is hidden by 4-5 concurrent blocks (R0/R1 evidence:
// block TLP absorbed full drains even with 3 blocks).
__global__ __launch_bounds__(256, 4) void fa_main(
    const float* __restrict__ Q, const u16* __restrict__ KB,
    const u16* __restrict__ VB, const void* __restrict__ cu_raw,
    int n_cu, float* __restrict__ O, int S, int n_qb)
{
    __shared__ __align__(16) u16 Kb[64 * 128];        // 16KB swizzled K tile
    __shared__ __align__(16) u16 Vt[128 * 64];        // 16KB V^T tile

    const int tid  = threadIdx.x;
    const int wave = tid >> 6, lane = tid & 63;
    const int quad = lane >> 4, l16 = lane & 15;
    const int h  = blockIdx.x & (HEADS - 1);          // heads vary fastest:
    const int qb = (n_qb - 1) - (blockIdx.x >> 4);    // all long blocks first
    const int q0 = qb * QT;

    const float sc2 = 0.08838834764831845f * 1.4426950408889634f; // scale*log2e
    const long hb = (long)h * S * DIM;
    const long hk = (long)h * (S >> 6) * 8192;        // u16 per head in KB/VB
    const int qend = q0 + QT;

    // cu_seqlens straight from global (L2-hot, read once per thread) — frees
    // the LDS bytes that previously blocked the 5th block/CU.
    const int qi_l = q0 + wave * 16 + l16;            // this lane's q-row
    int qs = 0, q0s = 0;
    {
        const int* cu32 = (const int*)cu_raw;
        const long long* cu64 = (const long long*)cu_raw;
        bool is64 = (cu32[1] == 0);
        for (int j = 0; j < n_cu; ++j) {
            int v = is64 ? (int)cu64[j] : cu32[j];
            if (v <= qi_l) qs = v;
            if (v <= q0)   q0s = v;
        }
    }
    const int drange = qi_l - qs;                     // mask range (>= 0)

    // Q fragments, fp32 -> bf16 once (B operand of swapped QK^T)
    bf16x8 qfrag[4];
    {
        const float* qp = Q + hb + (long)qi_l * DIM + quad * 8;
#pragma unroll
        for (int kk = 0; kk < 4; ++kk) {
            f32x4 x = *(const f32x4*)(qp + kk * 32);
            f32x4 y = *(const f32x4*)(qp + kk * 32 + 4);
            u16x8 u;
            u[0]=f2bf(x[0]); u[1]=f2bf(x[1]); u[2]=f2bf(x[2]); u[3]=f2bf(x[3]);
            u[4]=f2bf(y[0]); u[5]=f2bf(y[1]); u[6]=f2bf(y[2]); u[7]=f2bf(y[3]);
            qfrag[kk] = __builtin_bit_cast(bf16x8, u);
        }
    }

    // ones-column B-fragment in registers: col l16==0 is all-ones.
    bf16x8 ones;
    {
        u16 ov = (l16 == 0) ? (u16)0x3F80 : (u16)0;
        u16x8 ou;
#pragma unroll
        for (int j = 0; j < 8; ++j) ou[j] = ov;
        ones = __builtin_bit_cast(bf16x8, ou);
    }

    f32x4 acc[9];                                     // [8] = row-sum (ones col)
#pragma unroll
    for (int dt = 0; dt < 9; ++dt) acc[dt] = (f32x4){0.f, 0.f, 0.f, 0.f};

    const int t0 = (q0s & ~(KTILE - 1)) >> 6;
    const int ntile = (qend >> 6) - t0;               // >= 1 always
    const u16* ksrc = KB + hk;
    const u16* vsrc = VB + hk;

    for (int i = 0; i < ntile; ++i) {
        // stage tile i (single buffer; prior iteration's end barrier
        // guarantees all waves finished reading the previous tile)
        {
            long off = (long)(t0 + i) * 8192;
#pragma unroll
            for (int c = 0; c < 4; ++c) {
                int ch = wave * 4 + c;                // 0..15
                dma16(ksrc + off + ch * 512 + lane * 8, &Kb[ch * 512]);
                dma16(vsrc + off + ch * 512 + lane * 8, &Vt[ch * 512]);
            }
        }
        asm volatile("s_waitcnt vmcnt(0)" ::: "memory");
        __builtin_amdgcn_s_barrier();                 // tile i staged & visible

        const int kt = (t0 + i) << 6;

        // ---- S^T = K Q^T (swapped): lane l16 = q-row, quad*4+r = k.
        // exp2/mask/cvtpk for sub-tile nt-1 is interleaved in PROGRAM ORDER
        // after QK(nt)'s MFMAs: trans/VALU ops fill the matrix pipe's shadow.
        f32x4 sc[4];
        unsigned Ra[4], Rb[4];
        const int base0 = (kt - qs) + quad * 4;       // per-lane mask base
#pragma unroll
        for (int nt = 0; nt < 4; ++nt) sc[nt] = (f32x4){0.f, 0.f, 0.f, 0.f};

#define EXP2N(n)                                                              \
        {                                                                     \
            int b_ = base0 + (n) * 16;                                        \
            float p0 = ((unsigned)(b_ + 0) <= (unsigned)drange)               \
                           ? __builtin_amdgcn_exp2f(sc[n][0] * sc2) : 0.f;    \
            float p1 = ((unsigned)(b_ + 1) <= (unsigned)drange)               \
                           ? __builtin_amdgcn_exp2f(sc[n][1] * sc2) : 0.f;    \
            float p2 = ((unsigned)(b_ + 2) <= (unsigned)drange)               \
                           ? __builtin_amdgcn_exp2f(sc[n][2] * sc2) : 0.f;    \
            float p3 = ((unsigned)(b_ + 3) <= (unsigned)drange)               \
                           ? __builtin_amdgcn_exp2f(sc[n][3] * sc2) : 0.f;    \
            Ra[n] = cvtpk(p0, p1);                                            \
            Rb[n] = cvtpk(p2, p3);                                            \
        }

        __builtin_amdgcn_s_setprio(1);
#pragma unroll
        for (int nt = 0; nt < 4; ++nt) {
#pragma unroll
            for (int kk = 0; kk < 4; ++kk) {
                int row = nt * 16 + l16;
                int g = kk * 4 + quad;
                u16x8 bu = *(const u16x8*)&Kb[row * 128 + ((g ^ (row & 7)) << 3)];
                sc[nt] = __builtin_amdgcn_mfma_f32_16x16x32_bf16(
                    __builtin_bit_cast(bf16x8, bu), qfrag[kk], sc[nt], 0, 0, 0);
            }
            if (nt >= 1) EXP2N(nt - 1);
        }
        EXP2N(3);
#undef EXP2N

        // ---- O += P V ; acc[8] accumulates row-sum l via ones column
#pragma unroll
        for (int kk2 = 0; kk2 < 2; ++kk2) {
            unsigned a0 = Ra[2*kk2], a1 = Ra[2*kk2 + 1];
            unsigned b0 = Rb[2*kk2], b1 = Rb[2*kk2 + 1];
            asm("v_permlane32_swap_b32 %0, %1" : "+v"(a0), "+v"(a1));
            asm("v_permlane16_swap_b32 %0, %1" : "+v"(a0), "+v"(a1));
            asm("v_permlane32_swap_b32 %0, %1" : "+v"(b0), "+v"(b1));
            asm("v_permlane16_swap_b32 %0, %1" : "+v"(b0), "+v"(b1));
            u32x4 wv; wv[0] = a0; wv[1] = b0; wv[2] = a1; wv[3] = b1;
            bf16x8 ap = __builtin_bit_cast(bf16x8, wv);

            int g2 = kk2 * 4 + quad;
#pragma unroll
            for (int dt = 0; dt < 8; ++dt) {
                int d = dt * 16 + l16;
                u16x8 bu = *(const u16x8*)&Vt[(d << 6) + ((g2 ^ (d & 7)) << 3)];
                acc[dt] = __builtin_amdgcn_mfma_f32_16x16x32_bf16(
                    ap, __builtin_bit_cast(bf16x8, bu), acc[dt], 0, 0, 0);
            }
            acc[8] = __builtin_amdgcn_mfma_f32_16x16x32_bf16(
                ap, ones, acc[8], 0, 0, 0);
        }
        __builtin_amdgcn_s_setprio(0);

        __builtin_amdgcn_s_barrier();                 // reads done before next DMA
    }

    // ---- epilogue: l for row quad*4+r sits in acc[8][r] of lane quad*16
#pragma unroll
    for (int r = 0; r < 4; ++r) {
        float l = __shfl(acc[8][r], (lane & 48), 64);
        int qi = q0 + wave * 16 + quad * 4 + r;
        float inv = 1.f / l;
        float* op = O + hb + (long)qi * DIM + l16;
#pragma unroll
        for (int dt = 0; dt < 8; ++dt)
            op[dt * 16] = acc[dt][r] * inv;
    }
}

// ---------------- fallback (round-1 kernel, used only if ws too small) ------
__global__ __launch_bounds__(256, 2) void fa_fallback(
    const float* __restrict__ Q, const float* __restrict__ K,
    const float* __restrict__ V, const void* __restrict__ cu_raw,
    int n_cu, float* __restrict__ O, int S)
{
    __shared__ __align__(16) u16 Kb[KTILE * KSTR];
    __shared__ __align__(16) u16 Vt[DIM * VSTR];
    __shared__ __align__(16) u16 Pw[4][16 * PSTR];
    __shared__ int cu_s[32];

    const int tid  = threadIdx.x;
    const int wave = tid >> 6, lane = tid & 63;
    const int quad = lane >> 4, l16 = lane & 15;
    const int q0   = blockIdx.x * QT;
    const int h    = blockIdx.y;
    const int cg = tid & 31, rr = tid >> 5;
    const int dv = tid & 127, hiv = tid >> 7;

    {
        const int* cu32 = (const int*)cu_raw;
        bool is64 = (cu32[1] == 0);
        for (int t = tid; t < n_cu; t += blockDim.x)
            cu_s[t] = is64 ? (int)((const long long*)cu_raw)[t] : cu32[t];
    }
    __syncthreads();

    const long hb = (long)h * S * DIM;
    const float NEG_INF = -__builtin_inff();
    const float scale = 0.08838834764831845f;

    int qstart[4];
#pragma unroll
    for (int r = 0; r < 4; ++r) {
        int qi = q0 + wave * 16 + quad * 4 + r;
        int st = 0;
        for (int j = 0; j < n_cu; ++j) if (cu_s[j] <= qi) st = cu_s[j];
        qstart[r] = st;
    }
    int q0s = 0;
    for (int j = 0; j < n_cu; ++j) if (cu_s[j] <= q0) q0s = cu_s[j];

    bf16x8 qfrag[4];
    {
        const float* qp = Q + hb + (long)(q0 + wave * 16 + l16) * DIM + quad * 8;
#pragma unroll
        for (int kk = 0; kk < 4; ++kk) {
            f32x4 x = *(const f32x4*)(qp + kk * 32);
            f32x4 y = *(const f32x4*)(qp + kk * 32 + 4);
            u16x8 u;
            u[0]=f2bf(x[0]); u[1]=f2bf(x[1]); u[2]=f2bf(x[2]); u[3]=f2bf(x[3]);
            u[4]=f2bf(y[0]); u[5]=f2bf(y[1]); u[6]=f2bf(y[2]); u[7]=f2bf(y[3]);
            qfrag[kk] = __builtin_bit_cast(bf16x8, u);
        }
    }

    f32x4 acc[8];
#pragma unroll
    for (int dt = 0; dt < 8; ++dt) acc[dt] = (f32x4){0.f, 0.f, 0.f, 0.f};
    float m_r[4], l_r[4];
#pragma unroll
    for (int r = 0; r < 4; ++r) { m_r[r] = NEG_INF; l_r[r] = 0.f; }

    for (int kt = q0s & ~(KTILE - 1); kt < q0 + QT; kt += KTILE) {
        __syncthreads();
        {
#pragma unroll
            for (int it = 0; it < 8; ++it) {
                f32x4 kx = *(const f32x4*)(K + hb + (long)(kt + rr + it*8) * DIM + cg*4);
                u16x4 kb4;
                kb4[0]=f2bf(kx[0]); kb4[1]=f2bf(kx[1]);
                kb4[2]=f2bf(kx[2]); kb4[3]=f2bf(kx[3]);
                *(u16x4*)&Kb[(rr + it*8) * KSTR + cg*4] = kb4;
            }
#pragma unroll
            for (int p = 0; p < 8; ++p) {
                int kq = 2*p + hiv;
                const float* vp = V + hb + (long)(kt + kq*4) * DIM + dv;
                u16x4 w;
                w[0]=f2bf(vp[0]); w[1]=f2bf(vp[(long)DIM]);
                w[2]=f2bf(vp[(long)2*DIM]); w[3]=f2bf(vp[(long)3*DIM]);
                *(u16x4*)&Vt[dv * VSTR + kq*4] = w;
            }
        }
        __syncthreads();

        f32x4 sc[4];
#pragma unroll
        for (int nt = 0; nt < 4; ++nt) sc[nt] = (f32x4){0.f, 0.f, 0.f, 0.f};
#pragma unroll
        for (int kk = 0; kk < 4; ++kk)
#pragma unroll
            for (int nt = 0; nt < 4; ++nt) {
                u16x8 bu = *(const u16x8*)&Kb[(nt*16 + l16) * KSTR + kk*32 + quad*8];
                sc[nt] = __builtin_amdgcn_mfma_f32_16x16x32_bf16(
                    qfrag[kk], __builtin_bit_cast(bf16x8, bu), sc[nt], 0, 0, 0);
            }
#pragma unroll
        for (int nt = 0; nt < 4; ++nt) {
            int kj = kt + nt * 16 + l16;
#pragma unroll
            for (int r = 0; r < 4; ++r) {
                int qi = q0 + wave * 16 + quad * 4 + r;
                bool ok = (kj >= qstart[r]) && (kj <= qi);
                sc[nt][r] = ok ? sc[nt][r] * scale : NEG_INF;
            }
        }
        float mnew[4], alpha[4], rsum[4];
#pragma unroll
        for (int r = 0; r < 4; ++r) {
            float tm = fmaxf(fmaxf(sc[0][r], sc[1][r]), fmaxf(sc[2][r], sc[3][r]));
#pragma unroll
            for (int off = 1; off < 16; off <<= 1)
                tm = fmaxf(tm, __shfl_xor(tm, off, 64));
            float mn = fmaxf(m_r[r], tm);
            mnew[r]  = mn;
            alpha[r] = (mn == NEG_INF) ? 1.f : __expf(m_r[r] - mn);
            rsum[r]  = 0.f;
        }
#pragma unroll
        for (int nt = 0; nt < 4; ++nt)
#pragma unroll
            for (int r = 0; r < 4; ++r) {
                float pv = (sc[nt][r] == NEG_INF) ? 0.f : __expf(sc[nt][r] - mnew[r]);
                sc[nt][r] = pv;
                rsum[r] += pv;
            }
#pragma unroll
        for (int r = 0; r < 4; ++r) {
            float s = rsum[r];
#pragma unroll
            for (int off = 1; off < 16; off <<= 1) s += __shfl_xor(s, off, 64);
            l_r[r] = l_r[r] * alpha[r] + s;
            m_r[r] = mnew[r];
        }
#pragma unroll
        for (int dt = 0; dt < 8; ++dt)
#pragma unroll
            for (int r = 0; r < 4; ++r) acc[dt][r] *= alpha[r];

#pragma unroll
        for (int nt = 0; nt < 4; ++nt)
#pragma unroll
            for (int r = 0; r < 4; ++r)
                Pw[wave][(quad*4 + r) * PSTR + ((nt ^ quad) * 16 + l16)] = f2bf(sc[nt][r]);

#pragma unroll
        for (int kk2 = 0; kk2 < 2; ++kk2) {
            int colx = (kk2*32 + quad*8) ^ ((l16 >> 2) << 4);
            u16x8 au = *(const u16x8*)&Pw[wave][l16 * PSTR + colx];
            bf16x8 ap = __builtin_bit_cast(bf16x8, au);
#pragma unroll
            for (int dt = 0; dt < 8; ++dt) {
                int base = (dt*16 + l16) * VSTR + kk2*32 + quad*8;
                u16x4 lo = *(const u16x4*)&Vt[base];
                u16x4 hi = *(const u16x4*)&Vt[base + 4];
                u16x8 bu;
                bu[0]=lo[0]; bu[1]=lo[1]; bu[2]=lo[2]; bu[3]=lo[3];
                bu[4]=hi[0]; bu[5]=hi[1]; bu[6]=hi[2]; bu[7]=hi[3];
                acc[dt] = __builtin_amdgcn_mfma_f32_16x16x32_bf16(
                    ap, __builtin_bit_cast(bf16x8, bu), acc[dt], 0, 0, 0);
            }
        }
    }

#pragma unroll
    for (int r = 0; r < 4; ++r) {
        int qi = q0 + wave * 16 + quad * 4 + r;
        float inv = 1.f / l_r[r];
        float* op = O + hb + (long)qi * DIM + l16;
#pragma unroll
        for (int dt = 0; dt < 8; ++dt)
            op[dt * 16] = acc[dt][r] * inv;
    }
}

extern "C" void kernel_launch(void* const* d_in, const int* in_sizes, int n_in,
                              void* d_out, int out_size, void* d_ws, size_t ws_size,
                              hipStream_t stream) {
    const float* q = (const float*)d_in[0];
    const float* k = (const float*)d_in[1];
    const float* v = (const float*)d_in[2];
    const void* cu = d_in[3];
    int n_cu = in_sizes[3];
    int S = in_sizes[0] / (HEADS * DIM);
    size_t perMat = (size_t)HEADS * S * 256;      // bytes of bf16 tiles per matrix
    if (ws_size >= 2 * perMat) {
        u16* KB = (u16*)d_ws;
        u16* VB = (u16*)((char*)d_ws + perMat);
        prep_kv<<<dim3(HEADS * (S >> 6)), 256, 0, stream>>>(k, v, KB, VB, S);
        int n_qb = S / QT;
        fa_main<<<dim3(n_qb * HEADS), 256, 0, stream>>>(
            q, KB, VB, cu, n_cu, (float*)d_out, S, n_qb);
    } else {
        fa_fallback<<<dim3(S / QT, HEADS), 256, 0, stream>>>(
            q, k, v, cu, n_cu, (float*)d_out, S);
    }
}

// Round 15
// 171.835 us; speedup vs baseline: 1.0349x; 1.0274x over previous
//
#include <hip/hip_runtime.h>

typedef float  f32x4  __attribute__((ext_vector_type(4)));
typedef __bf16 bf16x8 __attribute__((ext_vector_type(8)));
typedef unsigned short u16;
typedef u16 u16x8 __attribute__((ext_vector_type(8)));
typedef u16 u16x4 __attribute__((ext_vector_type(4)));
typedef unsigned u32x4 __attribute__((ext_vector_type(4)));

#define HEADS 16
#define DIM   128
#define QT    64    // q-rows per block (4 waves x 16 rows)
#define KTILE 64
#define PSTR  72    // fallback P staging row stride (u16)
// fallback kernel strides
#define KSTR  136
#define VSTR  68

__device__ __forceinline__ u16 f2bf(float f) {
    unsigned u = __builtin_bit_cast(unsigned, f);
    u += 0x7FFFu + ((u >> 16) & 1u);   // RNE
    return (u16)(u >> 16);
}

// async 16B global->LDS DMA (zero VGPR cost); lane i lands at ldsbase + i*16
__device__ __forceinline__ void dma16(const void* g, void* l) {
    auto* gp = (const __attribute__((address_space(1))) unsigned*)(uintptr_t)g;
    auto* lp = (__attribute__((address_space(3))) unsigned*)(uintptr_t)l;
    __builtin_amdgcn_global_load_lds(gp, lp, 16, 0, 0);
}

// pack two f32 -> one u32 of 2 bf16 (RNE), in-register
__device__ __forceinline__ unsigned cvtpk(float lo, float hi) {
    unsigned r;
    asm("v_cvt_pk_bf16_f32 %0, %1, %2" : "=v"(r) : "v"(lo), "v"(hi));
    return r;
}

// ---------------- fused prep kernel: fp32 -> bf16, tiled + XOR-swizzled -----
// One block per (h, tile). Produces BOTH the K image and the V^T image.
// K tile image (16KB): row r(key 0..63) * 256B; 16B-group g(d/8) at (g ^ (r&7))
// V tile image (16KB), TRANSPOSED via LDS: row d(0..127)*128B; group g2(k/8) at (g2 ^ (d&7))
__global__ __launch_bounds__(256) void prep_kv(
    const float* __restrict__ K, const float* __restrict__ V,
    u16* __restrict__ KB, u16* __restrict__ VB, int S)
{
    __shared__ __align__(16) u16 T[128 * 72];     // [d][k], stride 72 (pad)
    int nt = S >> 6;
    int tile = blockIdx.x % nt, h = blockIdx.x / nt;
    int t = threadIdx.x;
    long tb = (long)(h * nt + tile) * 8192;       // u16 per tile

    // ---- K part: straight global->global swizzled copy+convert
    const float* ksrc = K + ((long)(h * S + tile * 64)) * DIM;
#pragma unroll
    for (int it = 0; it < 4; ++it) {
        int idx = t + it * 256;                   // 16B output group id 0..1023
        int g = idx & 15, r = idx >> 4;
        const float* src = ksrc + (long)r * DIM + g * 8;
        f32x4 a = *(const f32x4*)src;
        f32x4 b = *(const f32x4*)(src + 4);
        u16x8 o;
        o[0]=f2bf(a[0]); o[1]=f2bf(a[1]); o[2]=f2bf(a[2]); o[3]=f2bf(a[3]);
        o[4]=f2bf(b[0]); o[5]=f2bf(b[1]); o[6]=f2bf(b[2]); o[7]=f2bf(b[3]);
        *(u16x8*)&KB[tb + r * 128 + ((g ^ (r & 7)) << 3)] = o;
    }

    // ---- V part: coalesced reads, LDS transpose, coalesced writes
    int col4 = (t & 31) * 4;                      // d base
    int row  = t >> 5;                            // k base 0..7
    const float* vsrc = V + ((long)(h * S + tile * 64)) * DIM;
#pragma unroll
    for (int it = 0; it < 8; ++it) {
        int k = row + it * 8;
        f32x4 x = *(const f32x4*)(vsrc + (long)k * DIM + col4);
        T[(col4 + 0) * 72 + k] = f2bf(x[0]);
        T[(col4 + 1) * 72 + k] = f2bf(x[1]);
        T[(col4 + 2) * 72 + k] = f2bf(x[2]);
        T[(col4 + 3) * 72 + k] = f2bf(x[3]);
    }
    __syncthreads();
#pragma unroll
    for (int it = 0; it < 4; ++it) {
        int idx = t + it * 256;                   // 16B chunk id 0..1023
        int d = idx >> 3, g2 = idx & 7;
        u16x8 o = *(const u16x8*)&T[d * 72 + g2 * 8];
        *(u16x8*)&VB[tb + d * 64 + ((g2 ^ (d & 7)) << 3)] = o;
    }
}

// ------- main flash kernel: R7 pipeline + head-grouped XCD swizzle ----------
// Single change vs the 56.2us R7 kernel: blocks are grouped so each XCD works
// on exactly 2 heads -> their K+V images (4MB) fit that XCD's private L2.
// Without this, every XCD touches all 16 heads (32MB) and all DMA staging
// comes from L3 (~500-900cy latency + 250MB/dispatch of L3 traffic).
__global__ __launch_bounds__(256, 2) void fa_main(
    const float* __restrict__ Q, const u16* __restrict__ KB,
    const u16* __restrict__ VB, const void* __restrict__ cu_raw,
    int n_cu, float* __restrict__ O, int S, int n_qb)
{
    __shared__ __align__(16) u16 Kb[2][64 * 128];     // 2x16KB swizzled K tiles
    __shared__ __align__(16) u16 Vt[2][128 * 64];     // 2x16KB V^T tiles
    __shared__ int cu_s[32];

    const int tid  = threadIdx.x;
    const int wave = tid >> 6, lane = tid & 63;
    const int quad = lane >> 4, l16 = lane & 15;

    // head-grouped XCD swizzle (bijective when total%16==0): blockIdx round-
    // robins across XCDs, so xcd=bid&7 pins each XCD to heads {2x,2x+1};
    // j>>1 walks q-blocks long-first. Falls back to the R7 mapping otherwise.
    int h, qb;
    {
        int bid = blockIdx.x;
        int total = n_qb * HEADS;
        if ((total & 15) == 0) {
            int xcd = bid & 7, j = bid >> 3;
            h  = xcd * 2 + (j & 1);
            qb = (n_qb - 1) - (j >> 1);
        } else {
            h  = bid & (HEADS - 1);
            qb = (n_qb - 1) - (bid >> 4);
        }
    }
    const int q0 = qb * QT;

    {   // cu_seqlens int64/int32 sniff
        const int* cu32 = (const int*)cu_raw;
        bool is64 = (cu32[1] == 0);
        for (int t = tid; t < n_cu; t += blockDim.x)
            cu_s[t] = is64 ? (int)((const long long*)cu_raw)[t] : cu32[t];
    }
    __syncthreads();

    const float sc2 = 0.08838834764831845f * 1.4426950408889634f; // scale*log2e
    const long hb = (long)h * S * DIM;
    const long hk = (long)h * (S >> 6) * 8192;        // u16 per head in KB/VB
    const int qend = q0 + QT;

    // swapped QK^T: this lane's q-row is l16-based (one per lane)
    const int qi_l = q0 + wave * 16 + l16;
    int qs = 0;
    for (int j = 0; j < n_cu; ++j) if (cu_s[j] <= qi_l) qs = cu_s[j];
    int q0s = 0;
    for (int j = 0; j < n_cu; ++j) if (cu_s[j] <= q0) q0s = cu_s[j];
    const int drange = qi_l - qs;                     // mask range (>= 0)

    // Q fragments, fp32 -> bf16 once (B operand of swapped QK^T)
    bf16x8 qfrag[4];
    {
        const float* qp = Q + hb + (long)qi_l * DIM + quad * 8;
#pragma unroll
        for (int kk = 0; kk < 4; ++kk) {
            f32x4 x = *(const f32x4*)(qp + kk * 32);
            f32x4 y = *(const f32x4*)(qp + kk * 32 + 4);
            u16x8 u;
            u[0]=f2bf(x[0]); u[1]=f2bf(x[1]); u[2]=f2bf(x[2]); u[3]=f2bf(x[3]);
            u[4]=f2bf(y[0]); u[5]=f2bf(y[1]); u[6]=f2bf(y[2]); u[7]=f2bf(y[3]);
            qfrag[kk] = __builtin_bit_cast(bf16x8, u);
        }
    }

    // ones-column B-fragment in registers: col l16==0 is all-ones.
    bf16x8 ones;
    {
        u16 ov = (l16 == 0) ? (u16)0x3F80 : (u16)0;
        u16x8 ou;
#pragma unroll
        for (int j = 0; j < 8; ++j) ou[j] = ov;
        ones = __builtin_bit_cast(bf16x8, ou);
    }

    f32x4 acc[9];                                     // [8] = row-sum (ones col)
#pragma unroll
    for (int dt = 0; dt < 9; ++dt) acc[dt] = (f32x4){0.f, 0.f, 0.f, 0.f};

    const int t0 = (q0s & ~(KTILE - 1)) >> 6;
    const int ntile = (qend >> 6) - t0;               // >= 1 always
    const u16* ksrc = KB + hk;
    const u16* vsrc = VB + hk;

    // prologue: stage tile t0 into buffer 0 (8 DMAs per wave)
    {
        long off = (long)t0 * 8192;
#pragma unroll
        for (int c = 0; c < 4; ++c) {
            int ch = wave * 4 + c;                    // 0..15
            dma16(ksrc + off + ch * 512 + lane * 8, &Kb[0][ch * 512]);
            dma16(vsrc + off + ch * 512 + lane * 8, &Vt[0][ch * 512]);
        }
    }

    for (int i = 0; i < ntile; ++i) {
        const int cur = i & 1;
        // prefetch tile i+1 into the other buffer (read-safe: end-of-prev-iter
        // barrier guaranteed all waves finished reading it)
        if (i + 1 < ntile) {
            long off = (long)(t0 + i + 1) * 8192;
#pragma unroll
            for (int c = 0; c < 4; ++c) {
                int ch = wave * 4 + c;
                dma16(ksrc + off + ch * 512 + lane * 8, &Kb[cur ^ 1][ch * 512]);
                dma16(vsrc + off + ch * 512 + lane * 8, &Vt[cur ^ 1][ch * 512]);
            }
            // 8 outstanding = tile i+1's; tile i's 8 (issued last iter) done
            asm volatile("s_waitcnt vmcnt(8)" ::: "memory");
        } else {
            asm volatile("s_waitcnt vmcnt(0)" ::: "memory");
        }
        __builtin_amdgcn_s_barrier();                 // all waves' tile-i DMA done

        const int kt = (t0 + i) << 6;
        const u16* kb = &Kb[cur][0];
        const u16* vt = &Vt[cur][0];

        // ---- S^T = K Q^T (swapped): lane l16 = q-row, quad*4+r = k.
        // exp2/mask/cvtpk for sub-tile nt-1 is interleaved in PROGRAM ORDER
        // after QK(nt)'s MFMAs: trans/VALU ops fill the matrix pipe's shadow.
        f32x4 sc[4];
        unsigned Ra[4], Rb[4];
        const int base0 = (kt - qs) + quad * 4;       // per-lane mask base
#pragma unroll
        for (int nt = 0; nt < 4; ++nt) sc[nt] = (f32x4){0.f, 0.f, 0.f, 0.f};

#define EXP2N(n)                                                              \
        {                                                                     \
            int b_ = base0 + (n) * 16;                                        \
            float p0 = ((unsigned)(b_ + 0) <= (unsigned)drange)               \
                           ? __builtin_amdgcn_exp2f(sc[n][0] * sc2) : 0.f;    \
            float p1 = ((unsigned)(b_ + 1) <= (unsigned)drange)               \
                           ? __builtin_amdgcn_exp2f(sc[n][1] * sc2) : 0.f;    \
            float p2 = ((unsigned)(b_ + 2) <= (unsigned)drange)               \
                           ? __builtin_amdgcn_exp2f(sc[n][2] * sc2) : 0.f;    \
            float p3 = ((unsigned)(b_ + 3) <= (unsigned)drange)               \
                           ? __builtin_amdgcn_exp2f(sc[n][3] * sc2) : 0.f;    \
            Ra[n] = cvtpk(p0, p1);                                            \
            Rb[n] = cvtpk(p2, p3);                                            \
        }

        __builtin_amdgcn_s_setprio(1);
#pragma unroll
        for (int nt = 0; nt < 4; ++nt) {
#pragma unroll
            for (int kk = 0; kk < 4; ++kk) {
                int row = nt * 16 + l16;
                int g = kk * 4 + quad;
                u16x8 bu = *(const u16x8*)&kb[row * 128 + ((g ^ (row & 7)) << 3)];
                sc[nt] = __builtin_amdgcn_mfma_f32_16x16x32_bf16(
                    __builtin_bit_cast(bf16x8, bu), qfrag[kk], sc[nt], 0, 0, 0);
            }
            if (nt >= 1) EXP2N(nt - 1);
        }
        EXP2N(3);
#undef EXP2N

        // ---- O += P V ; acc[8] accumulates row-sum l via ones column
#pragma unroll
        for (int kk2 = 0; kk2 < 2; ++kk2) {
            unsigned a0 = Ra[2*kk2], a1 = Ra[2*kk2 + 1];
            unsigned b0 = Rb[2*kk2], b1 = Rb[2*kk2 + 1];
            asm("v_permlane32_swap_b32 %0, %1" : "+v"(a0), "+v"(a1));
            asm("v_permlane16_swap_b32 %0, %1" : "+v"(a0), "+v"(a1));
            asm("v_permlane32_swap_b32 %0, %1" : "+v"(b0), "+v"(b1));
            asm("v_permlane16_swap_b32 %0, %1" : "+v"(b0), "+v"(b1));
            u32x4 wv; wv[0] = a0; wv[1] = b0; wv[2] = a1; wv[3] = b1;
            bf16x8 ap = __builtin_bit_cast(bf16x8, wv);

            int g2 = kk2 * 4 + quad;
#pragma unroll
            for (int dt = 0; dt < 8; ++dt) {
                int d = dt * 16 + l16;
                u16x8 bu = *(const u16x8*)&vt[(d << 6) + ((g2 ^ (d & 7)) << 3)];
                acc[dt] = __builtin_amdgcn_mfma_f32_16x16x32_bf16(
                    ap, __builtin_bit_cast(bf16x8, bu), acc[dt], 0, 0, 0);
            }
            acc[8] = __builtin_amdgcn_mfma_f32_16x16x32_bf16(
                ap, ones, acc[8], 0, 0, 0);
        }
        __builtin_amdgcn_s_setprio(0);

        __builtin_amdgcn_s_barrier();                 // reads of buf[cur] done
    }

    // ---- epilogue: l for row quad*4+r sits in acc[8][r] of lane quad*16
#pragma unroll
    for (int r = 0; r < 4; ++r) {
        float l = __shfl(acc[8][r], (lane & 48), 64);
        int qi = q0 + wave * 16 + quad * 4 + r;
        float inv = 1.f / l;
        float* op = O + hb + (long)qi * DIM + l16;
#pragma unroll
        for (int dt = 0; dt < 8; ++dt)
            op[dt * 16] = acc[dt][r] * inv;
    }
}

// ---------------- fallback (round-1 kernel, used only if ws too small) ------
__global__ __launch_bounds__(256, 2) void fa_fallback(
    const float* __restrict__ Q, const float* __restrict__ K,
    const float* __restrict__ V, const void* __restrict__ cu_raw,
    int n_cu, float* __restrict__ O, int S)
{
    __shared__ __align__(16) u16 Kb[KTILE * KSTR];
    __shared__ __align__(16) u16 Vt[DIM * VSTR];
    __shared__ __align__(16) u16 Pw[4][16 * PSTR];
    __shared__ int cu_s[32];

    const int tid  = threadIdx.x;
    const int wave = tid >> 6, lane = tid & 63;
    const int quad = lane >> 4, l16 = lane & 15;
    const int q0   = blockIdx.x * QT;
    const int h    = blockIdx.y;
    const int cg = tid & 31, rr = tid >> 5;
    const int dv = tid & 127, hiv = tid >> 7;

    {
        const int* cu32 = (const int*)cu_raw;
        bool is64 = (cu32[1] == 0);
        for (int t = tid; t < n_cu; t += blockDim.x)
            cu_s[t] = is64 ? (int)((const long long*)cu_raw)[t] : cu32[t];
    }
    __syncthreads();

    const long hb = (long)h * S * DIM;
    const float NEG_INF = -__builtin_inff();
    const float scale = 0.08838834764831845f;

    int qstart[4];
#pragma unroll
    for (int r = 0; r < 4; ++r) {
        int qi = q0 + wave * 16 + quad * 4 + r;
        int st = 0;
        for (int j = 0; j < n_cu; ++j) if (cu_s[j] <= qi) st = cu_s[j];
        qstart[r] = st;
    }
    int q0s = 0;
    for (int j = 0; j < n_cu; ++j) if (cu_s[j] <= q0) q0s = cu_s[j];

    bf16x8 qfrag[4];
    {
        const float* qp = Q + hb + (long)(q0 + wave * 16 + l16) * DIM + quad * 8;
#pragma unroll
        for (int kk = 0; kk < 4; ++kk) {
            f32x4 x = *(const f32x4*)(qp + kk * 32);
            f32x4 y = *(const f32x4*)(qp + kk * 32 + 4);
            u16x8 u;
            u[0]=f2bf(x[0]); u[1]=f2bf(x[1]); u[2]=f2bf(x[2]); u[3]=f2bf(x[3]);
            u[4]=f2bf(y[0]); u[5]=f2bf(y[1]); u[6]=f2bf(y[2]); u[7]=f2bf(y[3]);
            qfrag[kk] = __builtin_bit_cast(bf16x8, u);
        }
    }

    f32x4 acc[8];
#pragma unroll
    for (int dt = 0; dt < 8; ++dt) acc[dt] = (f32x4){0.f, 0.f, 0.f, 0.f};
    float m_r[4], l_r[4];
#pragma unroll
    for (int r = 0; r < 4; ++r) { m_r[r] = NEG_INF; l_r[r] = 0.f; }

    for (int kt = q0s & ~(KTILE - 1); kt < q0 + QT; kt += KTILE) {
        __syncthreads();
        {
#pragma unroll
            for (int it = 0; it < 8; ++it) {
                f32x4 kx = *(const f32x4*)(K + hb + (long)(kt + rr + it*8) * DIM + cg*4);
                u16x4 kb4;
                kb4[0]=f2bf(kx[0]); kb4[1]=f2bf(kx[1]);
                kb4[2]=f2bf(kx[2]); kb4[3]=f2bf(kx[3]);
                *(u16x4*)&Kb[(rr + it*8) * KSTR + cg*4] = kb4;
            }
#pragma unroll
            for (int p = 0; p < 8; ++p) {
                int kq = 2*p + hiv;
                const float* vp = V + hb + (long)(kt + kq*4) * DIM + dv;
                u16x4 w;
                w[0]=f2bf(vp[0]); w[1]=f2bf(vp[(long)DIM]);
                w[2]=f2bf(vp[(long)2*DIM]); w[3]=f2bf(vp[(long)3*DIM]);
                *(u16x4*)&Vt[dv * VSTR + kq*4] = w;
            }
        }
        __syncthreads();

        f32x4 sc[4];
#pragma unroll
        for (int nt = 0; nt < 4; ++nt) sc[nt] = (f32x4){0.f, 0.f, 0.f, 0.f};
#pragma unroll
        for (int kk = 0; kk < 4; ++kk)
#pragma unroll
            for (int nt = 0; nt < 4; ++nt) {
                u16x8 bu = *(const u16x8*)&Kb[(nt*16 + l16) * KSTR + kk*32 + quad*8];
                sc[nt] = __builtin_amdgcn_mfma_f32_16x16x32_bf16(
                    qfrag[kk], __builtin_bit_cast(bf16x8, bu), sc[nt], 0, 0, 0);
            }
#pragma unroll
        for (int nt = 0; nt < 4; ++nt) {
            int kj = kt + nt * 16 + l16;
#pragma unroll
            for (int r = 0; r < 4; ++r) {
                int qi = q0 + wave * 16 + quad * 4 + r;
                bool ok = (kj >= qstart[r]) && (kj <= qi);
                sc[nt][r] = ok ? sc[nt][r] * scale : NEG_INF;
            }
        }
        float mnew[4], alpha[4], rsum[4];
#pragma unroll
        for (int r = 0; r < 4; ++r) {
            float tm = fmaxf(fmaxf(sc[0][r], sc[1][r]), fmaxf(sc[2][r], sc[3][r]));
#pragma unroll
            for (int off = 1; off < 16; off <<= 1)
                tm = fmaxf(tm, __shfl_xor(tm, off, 64));
            float mn = fmaxf(m_r[r], tm);
            mnew[r]  = mn;
            alpha[r] = (mn == NEG_INF) ? 1.f : __expf(m_r[r] - mn);
            rsum[r]  = 0.f;
        }
#pragma unroll
        for (int nt = 0; nt < 4; ++nt)
#pragma unroll
            for (int r = 0; r < 4; ++r) {
                float pv = (sc[nt][r] == NEG_INF) ? 0.f : __expf(sc[nt][r] - mnew[r]);
                sc[nt][r] = pv;
                rsum[r] += pv;
            }
#pragma unroll
        for (int r = 0; r < 4; ++r) {
            float s = rsum[r];
#pragma unroll
            for (int off = 1; off < 16; off <<= 1) s += __shfl_xor(s, off, 64);
            l_r[r] = l_r[r] * alpha[r] + s;
            m_r[r] = mnew[r];
        }
#pragma unroll
        for (int dt = 0; dt < 8; ++dt)
#pragma unroll
            for (int r = 0; r < 4; ++r) acc[dt][r] *= alpha[r];

#pragma unroll
        for (int nt = 0; nt < 4; ++nt)
#pragma unroll
            for (int r = 0; r < 4; ++r)
                Pw[wave][(quad*4 + r) * PSTR + ((nt ^ quad) * 16 + l16)] = f2bf(sc[nt][r]);

#pragma unroll
        for (int kk2 = 0; kk2 < 2; ++kk2) {
            int colx = (kk2*32 + quad*8) ^ ((l16 >> 2) << 4);
            u16x8 au = *(const u16x8*)&Pw[wave][l16 * PSTR + colx];
            bf16x8 ap = __builtin_bit_cast(bf16x8, au);
#pragma unroll
            for (int dt = 0; dt < 8; ++dt) {
                int base = (dt*16 + l16) * VSTR + kk2*32 + quad*8;
                u16x4 lo = *(const u16x4*)&Vt[base];
                u16x4 hi = *(const u16x4*)&Vt[base + 4];
                u16x8 bu;
                bu[0]=lo[0]; bu[1]=lo[1]; bu[2]=lo[2]; bu[3]=lo[3];
                bu[4]=hi[0]; bu[5]=hi[1]; bu[6]=hi[2]; bu[7]=hi[3];
                acc[dt] = __builtin_amdgcn_mfma_f32_16x16x32_bf16(
                    ap, __builtin_bit_cast(bf16x8, bu), acc[dt], 0, 0, 0);
            }
        }
    }

#pragma unroll
    for (int r = 0; r < 4; ++r) {
        int qi = q0 + wave * 16 + quad * 4 + r;
        float inv = 1.f / l_r[r];
        float* op = O + hb + (long)qi * DIM + l16;
#pragma unroll
        for (int dt = 0; dt < 8; ++dt)
            op[dt * 16] = acc[dt][r] * inv;
    }
}

extern "C" void kernel_launch(void* const* d_in, const int* in_sizes, int n_in,
                              void* d_out, int out_size, void* d_ws, size_t ws_size,
                              hipStream_t stream) {
    const float* q = (const float*)d_in[0];
    const float* k = (const float*)d_in[1];
    const float* v = (const float*)d_in[2];
    const void* cu = d_in[3];
    int n_cu = in_sizes[3];
    int S = in_sizes[0] / (HEADS * DIM);
    size_t perMat = (size_t)HEADS * S * 256;      // bytes of bf16 tiles per matrix
    if (ws_size >= 2 * perMat) {
        u16* KB = (u16*)d_ws;
        u16* VB = (u16*)((char*)d_ws + perMat);
        prep_kv<<<dim3(HEADS * (S >> 6)), 256, 0, stream>>>(k, v, KB, VB, S);
        int n_qb = S / QT;
        fa_main<<<dim3(n_qb * HEADS), 256, 0, stream>>>(
            q, KB, VB, cu, n_cu, (float*)d_out, S, n_qb);
    } else {
        fa_fallback<<<dim3(S / QT, HEADS), 256, 0, stream>>>(
            q, k, v, cu, n_cu, (float*)d_out, S);
    }
}